// Round 3
// baseline (173.547 us; speedup 1.0000x reference)
//
#include <hip/hip_runtime.h>
#include <hip/hip_bf16.h>

// Chamfer distance, B=4, N=M=8192, D=3, fp32.
// d2(p,t) = |p|^2 + (|t|^2 - 2 p.t).
// DB chunk staged in LDS pair-transposed: row j = [x0 x1 y0 y1 z0 z1 w0 w1]
// (x = -2*t.x etc., w = |t|^2) so two DB points are processed with 3
// v_pk_fma_f32 + 1 min-pair per query (2 VALU instrs per pair).
// Queries are register-blocked Q=8 with EXPLICIT scalars (round-1 showed the
// compiler demoted arrays: VGPR_Count=28 => loop reroll, ~2x instructions).
// Partial mins combined via uint-bitpattern atomicMin (d2 >= 0); the
// last-arriving block reduces the 64K mins and writes the scalar output.

typedef float v2f __attribute__((ext_vector_type(2)));

#define T 256      // threads per block
#define Q 8        // query points per thread
#define S 16       // db splits
#define CH 512     // db chunk size (8192 / S)
#define NPTS 8192
#define NCOMBO 8   // 2 directions x 4 batches
#define NB (NCOMBO * 4 * S)   // 512 blocks

#define FOR8(OP) OP(0) OP(1) OP(2) OP(3) OP(4) OP(5) OP(6) OP(7)

__global__ __launch_bounds__(T) void chamfer_fused(
    const float* __restrict__ pred, const float* __restrict__ target,
    unsigned int* __restrict__ partmin, unsigned int* __restrict__ counter,
    const float* __restrict__ bpp, const float* __restrict__ lamda,
    float* __restrict__ out)
{
    __shared__ v2f s4[CH / 2 + 1][4];   // +1 row: prefetch overrun pad

    const int bid   = blockIdx.x;
    const int dbc   = bid & (S - 1);
    const int qc    = (bid >> 4) & 3;
    const int combo = bid >> 6;          // 0..7
    const int dir   = combo & 1;
    const int b     = combo >> 1;

    const float* qptr = (dir == 0 ? pred : target) + (size_t)b * NPTS * 3;
    const float* dptr = (dir == 0 ? target : pred) + (size_t)b * NPTS * 3;
    const int tid = threadIdx.x;

    // --- stage db chunk into LDS, transformed + pair-transposed ---
    for (int p = tid; p < CH; p += T) {
        int gj = dbc * CH + p;
        float x = dptr[gj * 3 + 0];
        float y = dptr[gj * 3 + 1];
        float z = dptr[gj * 3 + 2];
        float* f = (float*)s4 + (p >> 1) * 8 + (p & 1);
        f[0] = -2.f * x;
        f[2] = -2.f * y;
        f[4] = -2.f * z;
        f[6] = fmaf(x, x, fmaf(y, y, z * z));
    }

    // --- load Q query points into explicit scalar registers ---
    const int qbase = qc * (T * Q) + tid;
#define LOADQ(k) \
    const int   qi##k  = qbase + (k) * T; \
    const float qxs##k = qptr[qi##k * 3 + 0]; \
    const float qys##k = qptr[qi##k * 3 + 1]; \
    const float qzs##k = qptr[qi##k * 3 + 2]; \
    const v2f   qx##k  = {qxs##k, qxs##k}; \
    const v2f   qy##k  = {qys##k, qys##k}; \
    const v2f   qz##k  = {qzs##k, qzs##k}; \
    float m##k = 3.4e38f;
    FOR8(LOADQ)
#undef LOADQ

    __syncthreads();

    // --- main loop: 2 db points/iter, 1-deep prefetch ---
    v2f cx = s4[0][0], cy = s4[0][1], cz = s4[0][2], cw = s4[0][3];
#pragma unroll 2
    for (int j = 0; j < CH / 2; ++j) {
        v2f nx = s4[j + 1][0], ny = s4[j + 1][1],
            nz = s4[j + 1][2], nw = s4[j + 1][3];
#define BODY(k) { \
        v2f s = __builtin_elementwise_fma(cz, qz##k, cw); \
        s = __builtin_elementwise_fma(cy, qy##k, s); \
        s = __builtin_elementwise_fma(cx, qx##k, s); \
        m##k = fminf(m##k, fminf(s.x, s.y)); }
        FOR8(BODY)
#undef BODY
        cx = nx; cy = ny; cz = nz; cw = nw;
    }

    // --- epilogue: add |q|^2, clamp >= 0, atomicMin on bit pattern ---
#define EPI(k) { \
    float qq = fmaf(qxs##k, qxs##k, fmaf(qys##k, qys##k, qzs##k * qzs##k)); \
    float d2 = fmaxf(m##k + qq, 0.0f); \
    atomicMin(&partmin[combo * NPTS + qi##k], __float_as_uint(d2)); }
    FOR8(EPI)
#undef EPI

    // --- last-arriving block reduces everything ---
    __threadfence();   // release our atomicMins before counter bump
    __shared__ int lastFlag;
    if (tid == 0)
        lastFlag = (atomicAdd(counter, 1u) == (unsigned)(NB - 1));
    __syncthreads();
    if (lastFlag) {
        float s = 0.f;
        for (int i = tid; i < NCOMBO * NPTS; i += T)
            s += __uint_as_float(__hip_atomic_load(
                    &partmin[i], __ATOMIC_RELAXED, __HIP_MEMORY_SCOPE_AGENT));
#pragma unroll
        for (int off = 32; off; off >>= 1)
            s += __shfl_down(s, off, 64);
        __shared__ float red[4];
        int lane = tid & 63, wid = tid >> 6;
        if (lane == 0) red[wid] = s;
        __syncthreads();
        if (tid == 0)
            out[0] = (red[0] + red[1] + red[2] + red[3]) * (1.f / 32768.f)
                     + lamda[0] * bpp[0];
    }
}

extern "C" void kernel_launch(void* const* d_in, const int* in_sizes, int n_in,
                              void* d_out, int out_size, void* d_ws, size_t ws_size,
                              hipStream_t stream) {
    const float* pred   = (const float*)d_in[0];
    const float* target = (const float*)d_in[1];
    const float* bpp    = (const float*)d_in[2];
    const float* lamda  = (const float*)d_in[3];
    unsigned int* partmin = (unsigned int*)d_ws;
    unsigned int* counter = partmin + NCOMBO * NPTS;

    // partial mins -> huge positive float (0x7F7F7F7F ~ 3.39e38); counter -> 0
    (void)hipMemsetAsync(partmin, 0x7F, (size_t)NCOMBO * NPTS * sizeof(unsigned), stream);
    (void)hipMemsetAsync(counter, 0, sizeof(unsigned), stream);

    chamfer_fused<<<NB, T, 0, stream>>>(pred, target, partmin, counter,
                                        bpp, lamda, (float*)d_out);
}